// Round 5
// baseline (176.071 us; speedup 1.0000x reference)
//
#include <hip/hip_runtime.h>
#include <hip/hip_bf16.h>
#include <stdint.h>

// Problem constants
#define Bn 4
#define LQ 1024
#define LK 2048
#define Dm 1024
#define Hn 16
#define HD 64

typedef __attribute__((ext_vector_type(4))) float f32x4;
typedef __attribute__((ext_vector_type(16))) float f32x16;
typedef __attribute__((ext_vector_type(8))) short bf16x8;

__device__ __forceinline__ ushort f2bf(float f) {
  union { float f; uint32_t u; } v; v.f = f;
  uint32_t r = v.u + 0x7FFF + ((v.u >> 16) & 1);
  return (ushort)(r >> 16);
}

__device__ __forceinline__ uint32_t cvt_pk_bf16(float lo, float hi) {
  uint32_t r;
  asm("v_cvt_pk_bf16_f32 %0, %1, %2" : "=v"(r) : "v"(lo), "v"(hi));
  return r;
}

__device__ __forceinline__ float exp2v(float x) {  // D = 2^x
  float r;
  asm("v_exp_f32 %0, %1" : "=v"(r) : "v"(x));
  return r;
}

__device__ __forceinline__ void gload16(const void* g, void* lds) {
  __builtin_amdgcn_global_load_lds(
      (const __attribute__((address_space(1))) void*)g,
      (__attribute__((address_space(3))) void*)lds, 16, 0, 0);
}

__device__ __forceinline__ void wait_vm0_barrier() {
  asm volatile("s_waitcnt vmcnt(0)" ::: "memory");
  __builtin_amdgcn_s_barrier();
}

__device__ __forceinline__ void wait_all_barrier() {
  asm volatile("s_waitcnt vmcnt(0) lgkmcnt(0)" ::: "memory");
  __builtin_amdgcn_s_barrier();
}

// ---------------- weight transpose + cast: W[K][N] f32 -> Wt[N][K] bf16 ----------------
__global__ __launch_bounds__(256) void transpose_cast_kernel(
    const float* __restrict__ W, ushort* __restrict__ Wt, int K, int N) {
  __shared__ float tile[64][65];
  int k0 = blockIdx.x * 64, n0 = blockIdx.y * 64;
  int tx = threadIdx.x & 63, ty = threadIdx.x >> 6;
#pragma unroll
  for (int i = 0; i < 16; ++i) {
    int r = ty + i * 4;
    tile[r][tx] = W[(size_t)(k0 + r) * N + n0 + tx];
  }
  __syncthreads();
#pragma unroll
  for (int i = 0; i < 16; ++i) {
    int r = ty + i * 4;
    Wt[(size_t)(n0 + r) * K + k0 + tx] = f2bf(tile[tx][r]);
  }
}

// ---------------- elementwise f32 -> bf16 cast ----------------
__global__ __launch_bounds__(256) void cast_bf16_kernel(
    const float4* __restrict__ in, ushort4* __restrict__ out, int n4) {
  int i = blockIdx.x * blockDim.x + threadIdx.x;
  int stride = gridDim.x * blockDim.x;
  for (; i < n4; i += stride) {
    float4 v = in[i];
    out[i] = make_ushort4(f2bf(v.x), f2bf(v.y), f2bf(v.z), f2bf(v.w));
  }
}

// ---------------- LayerNorm over D=1024, f32 in -> bf16 out ----------------
__global__ __launch_bounds__(256) void ln_kernel(
    const float* __restrict__ x, const float* __restrict__ g,
    const float* __restrict__ b, ushort* __restrict__ y) {
  int row = blockIdx.x;
  const float4* xr = (const float4*)(x + (size_t)row * 1024);
  float4 v = xr[threadIdx.x];
  float s1 = v.x + v.y + v.z + v.w;
  float s2 = v.x * v.x + v.y * v.y + v.z * v.z + v.w * v.w;
#pragma unroll
  for (int off = 32; off > 0; off >>= 1) {
    s1 += __shfl_down(s1, off);
    s2 += __shfl_down(s2, off);
  }
  __shared__ float r1[4], r2[4];
  int w = threadIdx.x >> 6, lane = threadIdx.x & 63;
  if (lane == 0) { r1[w] = s1; r2[w] = s2; }
  __syncthreads();
  s1 = r1[0] + r1[1] + r1[2] + r1[3];
  s2 = r2[0] + r2[1] + r2[2] + r2[3];
  float mu = s1 * (1.0f / 1024.0f);
  float var = s2 * (1.0f / 1024.0f) - mu * mu;
  float rstd = rsqrtf(var + 1e-5f);
  float4 gv = ((const float4*)g)[threadIdx.x];
  float4 bv = ((const float4*)b)[threadIdx.x];
  ushort4 o;
  o.x = f2bf((v.x - mu) * rstd * gv.x + bv.x);
  o.y = f2bf((v.y - mu) * rstd * gv.y + bv.y);
  o.z = f2bf((v.z - mu) * rstd * gv.z + bv.z);
  o.w = f2bf((v.w - mu) * rstd * gv.w + bv.w);
  ((ushort4*)(y + (size_t)row * 1024))[threadIdx.x] = o;
}

// ---------------- GEMM: C[M][N] = A[M][K](bf16) @ Bt[N][K]^T(bf16) + bias ----------------
// 256 threads / 4 waves, 128x128 tile, BK=64, 32x32x16 MFMA, wave tile 64x64.
// EPI 0: bf16 out, value (acc+bias)*osc.  EPI 1: bf16 out scattered to Vt.  EPI 2: f32 + residual.
template <int EPI>
__global__ __launch_bounds__(256) void gemm_bt_kernel(
    const ushort* __restrict__ A, const ushort* __restrict__ Bt,
    const float* __restrict__ bias, void* __restrict__ Cout,
    const float* __restrict__ residual, int M, int N, int K, float osc) {
  __shared__ ushort As[2][128 * 64];
  __shared__ ushort Bs[2][128 * 64];
  const int t = threadIdx.x;
  const int lane = t & 63;
  const int w = t >> 6;
  const int wm = w >> 1, wn = w & 1;   // 2x2 wave grid: 64x64 per wave
  const int m0 = blockIdx.y * 128, n0 = blockIdx.x * 128;
  const int l31 = lane & 31, hl = lane >> 5;

  f32x16 acc[2][2] = {};

  // staging: 1024 16B chunks per matrix per K-step; 4 per thread per matrix
  const ushort* Ap[4];
  const ushort* Bp[4];
#pragma unroll
  for (int i = 0; i < 4; ++i) {
    int c = t + i * 256;
    int r = c >> 3, x = ((c & 7) ^ (r & 7)) * 8;
    Ap[i] = A + (size_t)(m0 + r) * K + x;
    Bp[i] = Bt + (size_t)(n0 + r) * K + x;
  }

  auto stage = [&](int buf, int kt) {
#pragma unroll
    for (int i = 0; i < 4; ++i) {
      gload16(Ap[i] + kt, (char*)As[buf] + (t + i * 256) * 16);
      gload16(Bp[i] + kt, (char*)Bs[buf] + (t + i * 256) * 16);
    }
  };

  stage(0, 0);
  wait_vm0_barrier();

  int cur = 0;
  for (int kt = 0; kt < K; kt += 64) {
    if (kt + 64 < K) stage(cur ^ 1, kt + 64);
    bf16x8 af[2][4], bfr[2][4];
#pragma unroll
    for (int m = 0; m < 2; ++m) {
      int row = wm * 64 + m * 32 + l31;
      const char* ar = (const char*)As[cur] + row * 128;
      int rs = row & 7;
#pragma unroll
      for (int kc = 0; kc < 4; ++kc)
        af[m][kc] = *(const bf16x8*)(ar + ((kc * 2 + hl) ^ rs) * 16);
    }
#pragma unroll
    for (int n = 0; n < 2; ++n) {
      int row = wn * 64 + n * 32 + l31;
      const char* br = (const char*)Bs[cur] + row * 128;
      int rs = row & 7;
#pragma unroll
      for (int kc = 0; kc < 4; ++kc)
        bfr[n][kc] = *(const bf16x8*)(br + ((kc * 2 + hl) ^ rs) * 16);
    }
#pragma unroll
    for (int kc = 0; kc < 4; ++kc)
#pragma unroll
      for (int m = 0; m < 2; ++m)
#pragma unroll
        for (int n = 0; n < 2; ++n)
          acc[m][n] = __builtin_amdgcn_mfma_f32_32x32x16_bf16(af[m][kc], bfr[n][kc], acc[m][n], 0, 0, 0);
    wait_vm0_barrier();
    cur ^= 1;
  }

  float bias_v[2];
#pragma unroll
  for (int n = 0; n < 2; ++n) bias_v[n] = bias[n0 + wn * 64 + n * 32 + l31];

#pragma unroll
  for (int m = 0; m < 2; ++m) {
    int rbase = m0 + wm * 64 + m * 32 + hl * 4;
#pragma unroll
    for (int n = 0; n < 2; ++n) {
      int col = n0 + wn * 64 + n * 32 + l31;
#pragma unroll
      for (int rq = 0; rq < 4; ++rq) {
        int row0 = rbase + rq * 8;
        if (EPI == 1) {
          int bb = row0 >> 11;        // / 2048
          int key = row0 & 2047;
          int h = col >> 6, hd = col & 63;
          ushort4 pk;
          pk.x = f2bf(acc[m][n][rq * 4 + 0] + bias_v[n]);
          pk.y = f2bf(acc[m][n][rq * 4 + 1] + bias_v[n]);
          pk.z = f2bf(acc[m][n][rq * 4 + 2] + bias_v[n]);
          pk.w = f2bf(acc[m][n][rq * 4 + 3] + bias_v[n]);
          *(ushort4*)((ushort*)Cout + ((size_t)((bb * 16 + h) * 64 + hd)) * 2048 + key) = pk;
        } else {
#pragma unroll
          for (int j = 0; j < 4; ++j) {
            int row = row0 + j;
            if (EPI == 0) {
              float v = (acc[m][n][rq * 4 + j] + bias_v[n]) * osc;
              ((ushort*)Cout)[(size_t)row * N + col] = f2bf(v);
            } else {
              size_t idx = (size_t)row * N + col;
              ((float*)Cout)[idx] = acc[m][n][rq * 4 + j] + bias_v[n] + residual[idx];
            }
          }
        }
      }
    }
  }
}

// ---------------- fused flash attention (32x32 MFMA, in-register P) ----------------
// grid: 512 blocks (XCD-chunked), 256 threads = 4 waves, 32 q-rows/wave (QBLK=128).
// S^T = mfma(K, Q^T): lane pair (l, l+32) holds the 64-key P-row for q = lane&31.
// P -> PV B-frag built in-register (cvt_pk + shfl_xor(32)); O^T = mfma(V^T, P^T).
__global__ __launch_bounds__(256) void attn_kernel(
    const ushort* __restrict__ Qb, const ushort* __restrict__ Kb,
    const ushort* __restrict__ Vt, const int* __restrict__ mask,
    ushort* __restrict__ ctx) {
  __shared__ float mbias[2048];       // 8 KB
  __shared__ ushort Ks[2][64 * 64];   // [key][dim], XOR-swizzled rows, dbuf (16 KB)
  __shared__ ushort Vs[2][64 * 64];   // [dim][key], XOR-swizzled rows, dbuf (16 KB)
  __shared__ ushort obuf[4][32 * 64]; // per-wave output transpose buffer (16 KB)

  const int t = threadIdx.x, lane = t & 63, w = t >> 6;
  const int l31 = lane & 31, hl = lane >> 5;
  // XCD-chunked swizzle: 512 blocks, 8 XCDs, chunk=64
  int o = blockIdx.x;
  int logical = (o & 7) * 64 + (o >> 3);
  const int b = logical >> 7;
  const int hh = (logical >> 3) & 15;    // head
  const int q0 = (logical & 7) * 128;
  const int* maskp = mask + b * 2048;

  // staging pointers (2 K-chunks + 2 V-chunks per thread per tile)
  const int cA = t, cB = t + 256;
  const int rA = cA >> 3, rB = cB >> 3;
  const int xA = ((cA & 7) ^ (rA & 7)) * 8, xB = ((cB & 7) ^ (rB & 7)) * 8;
  const ushort* kpA = Kb + ((size_t)(b * 2048 + rA)) * 1024 + hh * 64 + xA;
  const ushort* kpB = Kb + ((size_t)(b * 2048 + rB)) * 1024 + hh * 64 + xB;
  const ushort* vpA = Vt + ((size_t)((b * 16 + hh) * 64 + rA)) * 2048 + xA;
  const ushort* vpB = Vt + ((size_t)((b * 16 + hh) * 64 + rB)) * 2048 + xB;

  auto stageKV = [&](int buf) {
    gload16(kpA, (char*)Ks[buf] + cA * 16);
    gload16(kpB, (char*)Ks[buf] + cB * 16);
    gload16(vpA, (char*)Vs[buf] + cA * 16);
    gload16(vpB, (char*)Vs[buf] + cB * 16);
  };

  stageKV(0);
  for (int i = t; i < 2048; i += 256) mbias[i] = maskp[i] ? 0.0f : -1e30f;

  // Q B-frags (pre-scaled by 0.125*log2e at projection): qf[kc] = Q[q][kc*16 + hl*8 .. +7]
  bf16x8 qf[4];
  {
    int qrow = q0 + w * 32 + l31;
    const ushort* qp = Qb + ((size_t)(b * 1024 + qrow)) * 1024 + hh * 64 + hl * 8;
    qf[0] = *(const bf16x8*)(qp);
    qf[1] = *(const bf16x8*)(qp + 16);
    qf[2] = *(const bf16x8*)(qp + 32);
    qf[3] = *(const bf16x8*)(qp + 48);
  }

  f32x16 o_acc[2] = {};
  float m_run = -1e30f, l_run = 0.0f;

  wait_all_barrier();  // staged tile 0 (vmcnt) + mbias ds_writes (lgkmcnt)

  int cur = 0;
  for (int kt = 0; kt < 2048; kt += 64) {
    kpA += 64 * 1024; kpB += 64 * 1024; vpA += 64; vpB += 64;
    if (kt + 64 < 2048) stageKV(cur ^ 1);

    // S^T[key][q]: sacc[kb], key = kt + kb*32 + (r&3) + 8*(r>>2) + 4*hl, q = l31
    f32x16 sacc[2] = {};
    __builtin_amdgcn_s_setprio(1);
#pragma unroll
    for (int kb = 0; kb < 2; ++kb) {
      int row = kb * 32 + l31;
      const char* krow = (const char*)Ks[cur] + row * 128;
      int rs = row & 7;
#pragma unroll
      for (int kc = 0; kc < 4; ++kc) {
        bf16x8 kf = *(const bf16x8*)(krow + ((kc * 2 + hl) ^ rs) * 16);
        sacc[kb] = __builtin_amdgcn_mfma_f32_32x32x16_bf16(kf, qf[kc], sacc[kb], 0, 0, 0);
      }
    }
    __builtin_amdgcn_s_setprio(0);

    // mask-add + row max (lane-local 32 values + one cross-pair shuffle)
    float p[2][16];
    float tm = -1e30f;
#pragma unroll
    for (int kb = 0; kb < 2; ++kb)
#pragma unroll
      for (int rq = 0; rq < 4; ++rq) {
        float4 mb = *(const float4*)&mbias[kt + kb * 32 + rq * 8 + hl * 4];
        float v0 = sacc[kb][rq * 4 + 0] + mb.x;
        float v1 = sacc[kb][rq * 4 + 1] + mb.y;
        float v2 = sacc[kb][rq * 4 + 2] + mb.z;
        float v3 = sacc[kb][rq * 4 + 3] + mb.w;
        p[kb][rq * 4 + 0] = v0; p[kb][rq * 4 + 1] = v1;
        p[kb][rq * 4 + 2] = v2; p[kb][rq * 4 + 3] = v3;
        tm = fmaxf(tm, fmaxf(fmaxf(v0, v1), fmaxf(v2, v3)));
      }
    tm = fmaxf(tm, __shfl_xor(tm, 32));

    if (__any(tm - m_run > 11.5f)) {   // defer-max (= e^8 in ln units)
      float mn = fmaxf(m_run, tm);
      float al = exp2v(m_run - mn);
      m_run = mn;
      l_run *= al;
#pragma unroll
      for (int df = 0; df < 2; ++df)
#pragma unroll
        for (int r = 0; r < 16; ++r) o_acc[df][r] *= al;
    }

    // exp + pack (keys pairs are consecutive within each reg quad)
    float psum = 0.0f;
    uint32_t cpk[2][8];
#pragma unroll
    for (int kb = 0; kb < 2; ++kb)
#pragma unroll
      for (int rr = 0; rr < 8; ++rr) {
        float pa = exp2v(p[kb][2 * rr] - m_run);
        float pb = exp2v(p[kb][2 * rr + 1] - m_run);
        psum += pa + pb;
        cpk[kb][rr] = cvt_pk_bf16(pa, pb);
      }
    psum += __shfl_xor(psum, 32);
    l_run += psum;

    // PV: build P^T B-frags in-register, O^T += V^T P^T
    __builtin_amdgcn_s_setprio(1);
#pragma unroll
    for (int ks = 0; ks < 4; ++ks) {
      const int kb = ks >> 1, ci = (ks & 1) * 4;
      uint32_t send0 = hl ? cpk[kb][ci] : cpk[kb][ci + 2];
      uint32_t send1 = hl ? cpk[kb][ci + 1] : cpk[kb][ci + 3];
      uint32_t recv0 = (uint32_t)__shfl_xor((int)send0, 32);
      uint32_t recv1 = (uint32_t)__shfl_xor((int)send1, 32);
      uint32_t own0 = hl ? cpk[kb][ci + 2] : cpk[kb][ci];
      uint32_t own1 = hl ? cpk[kb][ci + 3] : cpk[kb][ci + 1];
      union { uint32_t u[4]; bf16x8 v; } pb_;
      pb_.u[0] = hl ? recv0 : own0;
      pb_.u[1] = hl ? recv1 : own1;
      pb_.u[2] = hl ? own0 : recv0;
      pb_.u[3] = hl ? own1 : recv1;
#pragma unroll
      for (int df = 0; df < 2; ++df) {
        int row = df * 32 + l31;
        bf16x8 vf = *(const bf16x8*)((const char*)Vs[cur] + row * 128 + ((ks * 2 + hl) ^ (row & 7)) * 16);
        o_acc[df] = __builtin_amdgcn_mfma_f32_32x32x16_bf16(vf, pb_.v, o_acc[df], 0, 0, 0);
      }
    }
    __builtin_amdgcn_s_setprio(0);

    wait_vm0_barrier();
    cur ^= 1;
  }

  // epilogue: normalize, transpose via wave-private LDS, coalesced store
  float inv = 1.0f / l_run;
  char* ob = (char*)obuf[w];
#pragma unroll
  for (int df = 0; df < 2; ++df)
#pragma unroll
    for (int rq = 0; rq < 4; ++rq) {
      ushort4 pk;
      pk.x = f2bf(o_acc[df][rq * 4 + 0] * inv);
      pk.y = f2bf(o_acc[df][rq * 4 + 1] * inv);
      pk.z = f2bf(o_acc[df][rq * 4 + 2] * inv);
      pk.w = f2bf(o_acc[df][rq * 4 + 3] * inv);
      *(ushort4*)(ob + l31 * 128 + (((df * 4 + rq) ^ (l31 & 7)) * 16) + hl * 8) = pk;
    }
  asm volatile("s_waitcnt lgkmcnt(0)" ::: "memory");
#pragma unroll
  for (int i = 0; i < 4; ++i) {
    int q = (lane >> 3) + i * 8;
    int ch = lane & 7;
    uint4 v = *(const uint4*)(ob + q * 128 + ((ch ^ (q & 7)) * 16));
    int qrow = q0 + w * 32 + q;
    *(uint4*)(ctx + ((size_t)(b * 1024 + qrow)) * 1024 + hh * 64 + ch * 8) = v;
  }
}

extern "C" void kernel_launch(void* const* d_in, const int* in_sizes, int n_in,
                              void* d_out, int out_size, void* d_ws, size_t ws_size,
                              hipStream_t stream) {
  const float* query = (const float*)d_in[0];
  const float* key   = (const float*)d_in[1];
  const float* value = (const float*)d_in[2];
  const int*   mask  = (const int*)d_in[3];
  const float* Wq = (const float*)d_in[4];
  const float* bq = (const float*)d_in[5];
  const float* Wk = (const float*)d_in[6];
  const float* bk = (const float*)d_in[7];
  const float* Wv = (const float*)d_in[8];
  const float* bv = (const float*)d_in[9];
  const float* Wo = (const float*)d_in[10];
  const float* bo = (const float*)d_in[11];
  const float* ln_g = (const float*)d_in[12];
  const float* ln_b = (const float*)d_in[13];
  float* out = (float*)d_out;

  char* p = (char*)d_ws;
  auto alloc = [&](size_t elems) { ushort* r = (ushort*)p; p += elems * 2; return r; };
  ushort* WqT  = alloc((size_t)1024 * 1024);
  ushort* WkT  = alloc((size_t)1024 * 512);
  ushort* WvT  = alloc((size_t)1024 * 512);
  ushort* WoT  = alloc((size_t)1024 * 1024);
  ushort* qn   = alloc((size_t)4096 * 1024);
  ushort* keyb = alloc((size_t)8192 * 512);
  ushort* valb = alloc((size_t)8192 * 512);
  ushort* Qb   = alloc((size_t)4096 * 1024);
  ushort* Kb   = alloc((size_t)8192 * 1024);
  ushort* Vt   = alloc((size_t)8192 * 1024);
  ushort* ctx  = alloc((size_t)4096 * 1024);
  (void)ws_size; (void)in_sizes; (void)n_in; (void)out_size;

  const float QSCALE = 0.125f * 1.44269504f;  // HD^-0.5 * log2(e), folded into Q

  dim3 blk(256);
  transpose_cast_kernel<<<dim3(16, 16), blk, 0, stream>>>(Wq, WqT, 1024, 1024);
  transpose_cast_kernel<<<dim3(8, 16),  blk, 0, stream>>>(Wk, WkT, 512, 1024);
  transpose_cast_kernel<<<dim3(8, 16),  blk, 0, stream>>>(Wv, WvT, 512, 1024);
  transpose_cast_kernel<<<dim3(16, 16), blk, 0, stream>>>(Wo, WoT, 1024, 1024);
  cast_bf16_kernel<<<dim3(1024), blk, 0, stream>>>((const float4*)key,   (ushort4*)keyb, (8192 * 512) / 4);
  cast_bf16_kernel<<<dim3(1024), blk, 0, stream>>>((const float4*)value, (ushort4*)valb, (8192 * 512) / 4);
  ln_kernel<<<dim3(4096), blk, 0, stream>>>(query, ln_g, ln_b, qn);

  gemm_bt_kernel<0><<<dim3(8, 32), blk, 0, stream>>>(qn,   WqT, bq, Qb, nullptr, 4096, 1024, 1024, QSCALE);
  gemm_bt_kernel<0><<<dim3(8, 64), blk, 0, stream>>>(keyb, WkT, bk, Kb, nullptr, 8192, 1024, 512, 1.0f);
  gemm_bt_kernel<1><<<dim3(8, 64), blk, 0, stream>>>(valb, WvT, bv, Vt, nullptr, 8192, 1024, 512, 1.0f);

  attn_kernel<<<dim3(512), blk, 0, stream>>>(Qb, Kb, Vt, mask, ctx);

  gemm_bt_kernel<2><<<dim3(8, 32), blk, 0, stream>>>(ctx, WoT, bo, out, query, 4096, 1024, 1024, 1.0f);
}